// Round 3
// baseline (164.475 us; speedup 1.0000x reference)
//
#include <hip/hip_runtime.h>
#include <hip/hip_bf16.h>

// Problem constants (from reference)
#define E_   16
#define B_   4096
#define DX_  128
#define DC_  64
#define DIN_ 192
#define DH_  1024
#define DO_  128

// Tile config: one block = one expert x 256 rows; DH chunked by 64.
#define BM 256
#define KC 64
#define NCHUNK (DH_ / KC)   // 16
#define NT 512              // 8 waves

typedef __attribute__((ext_vector_type(4))) float f32x4;
typedef __attribute__((ext_vector_type(8))) short bf16x8;

__device__ __forceinline__ unsigned f2bf_u(float f) {
    union { float f; unsigned u; } v; v.f = f;
    return (v.u + 0x7fffu + ((v.u >> 16) & 1u)) >> 16;   // RNE
}
__device__ __forceinline__ uint2 pack4(float4 v) {
    uint2 r;
    r.x = f2bf_u(v.x) | (f2bf_u(v.y) << 16);
    r.y = f2bf_u(v.z) | (f2bf_u(v.w) << 16);
    return r;
}
// Swizzled short-index: row r (row stride S shorts), byte-col cb.
// XOR byte-bits 4..6 with (r&7): rows whose base addrs are 128B-congruent
// (all three buffers: 384/128/128 B strides) spread across 8 distinct 16B
// slots -> b128 reads of 16-row column slices are 2-way (free, m136) not
// 16-way. Same formula on EVERY read and write (both-sides rule #21).
__device__ __forceinline__ int swz(int r, int S, int cb) {
    return r * S + ((cb ^ ((r & 7) << 4)) >> 1);
}

__global__ __launch_bounds__(NT, 2)
void moe_fused_kernel(const float* __restrict__ x, const float* __restrict__ cond,
                      const float* __restrict__ W1, const float* __restrict__ b1,
                      const float* __restrict__ W2, const float* __restrict__ b2,
                      float* __restrict__ out) {
    // 152 KB LDS total (<=160 KB), 1 block/CU, 8 waves = 2 waves/SIMD
    __shared__ short XCs[BM * DIN_];        // 96 KB  [256][192] bf16, swizzled
    __shared__ short WB [KC * DIN_];        // 24 KB  union: W1 chunk [64][192] / W2 chunk [128][64]
    __shared__ short HB [BM * KC];          // 32 KB  [256][64] relu(h) chunk

    // XCD swizzle: bid%8 = XCD (round-robin dispatch); XCD x owns experts {2x,2x+1}
    // -> per-XCD weight working set 2.5 MB fp32 < 4 MB L2.
    const int bid = blockIdx.x;             // 0..255
    const int xcd = bid & 7;
    const int s   = bid >> 3;               // 0..31
    const int e   = 2 * xcd + (s & 1);
    const int row0 = (s >> 1) * BM;

    const int tid  = threadIdx.x;
    const int w    = tid >> 6;              // wave 0..7
    const int lane = tid & 63;
    const int lr   = lane & 15;
    const int lg   = lane >> 4;

    const float4* g1base = (const float4*)(W1 + (size_t)e * DH_ * DIN_);

    // ---- T14 prologue: issue W1(chunk 0) loads; they fly during XC staging ----
    float4 r1[6];
#pragma unroll
    for (int i = 0; i < 6; ++i) r1[i] = g1base[tid + NT * i];

    // ---- stage XC = concat(x, cond) -> bf16 LDS (read-once from HBM) ----
    {
        const float4* gx = (const float4*)(x + (size_t)(e * B_ + row0) * DX_);
#pragma unroll
        for (int i = 0; i < 16; ++i) {              // 8192 float4 of x
            int g = tid + NT * i;
            int r = g >> 5, c = g & 31;             // 32 float4 per row
            *(uint2*)&XCs[swz(r, DIN_, c * 8)] = pack4(gx[g]);
        }
        const float4* gc = (const float4*)(cond + (size_t)(e * B_ + row0) * DC_);
#pragma unroll
        for (int i = 0; i < 8; ++i) {               // 4096 float4 of cond
            int g = tid + NT * i;
            int r = g >> 4, c = g & 15;             // 16 float4 per row
            // byte col 256+v: bit 8 is outside the XOR range -> 256+(v^s) == (256+v)^s
            *(uint2*)&XCs[128 + swz(r, DIN_, c * 8)] = pack4(gc[g]);
        }
    }

    f32x4 acc2[4][4] = {};   // y accumulator (64 VGPR), persists across chunks

    for (int c = 0; c < NCHUNK; ++c) {
        __syncthreads();   // A: WB free (prev G2 done); drains W1(c) loads (flew under G2 / XC stage)

        // ---- cvt+write W1 chunk c from regs -> WB bf16 (no global reads here) ----
#pragma unroll
        for (int i = 0; i < 6; ++i) {               // 3072 float4/block
            int g = tid + NT * i;
            int r = g / 48, cc = g - r * 48;        // 48 float4 per row of [64][192]
            *(uint2*)&WB[swz(r, DIN_, cc * 8)] = pack4(r1[i]);
        }
        __syncthreads();   // B: WB(W1) ready

        // ---- issue W2(c) loads AFTER barrier B: in flight during GEMM1 ----
        float4 r2[4];
        {
            const float* g2 = W2 + (size_t)e * DO_ * DH_ + (size_t)c * KC;
#pragma unroll
            for (int i = 0; i < 4; ++i) {           // 2048 float4/block
                int g = tid + NT * i;
                int r = g >> 4, cc = g & 15;        // 16 float4 per row of [128][64]
                r2[i] = *(const float4*)(g2 + (size_t)r * DH_ + cc * 4);
            }
        }
        float b1v[4];
#pragma unroll
        for (int nf = 0; nf < 4; ++nf)
            b1v[nf] = b1[e * DH_ + c * KC + nf * 16 + lr];

        // ---- GEMM1: h_chunk[256][64] = XC[256][192] @ W1c^T ----
        // wave mapping 8x1: each wave owns 32 rows x all 64 cols
        const int band = w * 32;
        f32x4 acc1[2][4] = {};
#pragma unroll
        for (int kk = 0; kk < DIN_ / 32; ++kk) {    // 6 k-steps
            bf16x8 af[2], bfr[4];
#pragma unroll
            for (int mf = 0; mf < 2; ++mf) {
                int r = band + mf * 16 + lr;
                af[mf] = *(const bf16x8*)&XCs[swz(r, DIN_, kk * 64 + lg * 16)];
            }
#pragma unroll
            for (int nf = 0; nf < 4; ++nf) {
                int r = nf * 16 + lr;
                bfr[nf] = *(const bf16x8*)&WB[swz(r, DIN_, kk * 64 + lg * 16)];
            }
#pragma unroll
            for (int mf = 0; mf < 2; ++mf)
#pragma unroll
                for (int nf = 0; nf < 4; ++nf)
                    acc1[mf][nf] = __builtin_amdgcn_mfma_f32_16x16x32_bf16(af[mf], bfr[nf], acc1[mf][nf], 0, 0, 0);
        }
        // ---- epilogue1: relu(acc1 + b1) -> HB bf16 ----
        // D layout (m89): row = lg*4 + j, col = lr
#pragma unroll
        for (int mf = 0; mf < 2; ++mf)
#pragma unroll
            for (int nf = 0; nf < 4; ++nf)
#pragma unroll
                for (int j = 0; j < 4; ++j) {
                    float v = fmaxf(acc1[mf][nf][j] + b1v[nf], 0.f);
                    int hr = band + mf * 16 + lg * 4 + j;
                    int hc = nf * 16 + lr;
                    HB[swz(hr, KC, 2 * hc)] = (short)f2bf_u(v);
                }
        __syncthreads();   // C: HB ready; waves done with WB(W1); drains r2 (landed under G1)

        // ---- cvt+write W2 chunk c from regs -> WB bf16 ----
#pragma unroll
        for (int i = 0; i < 4; ++i) {
            int g = tid + NT * i;
            int r = g >> 4, cc = g & 15;
            *(uint2*)&WB[swz(r, KC, cc * 8)] = pack4(r2[i]);
        }
        __syncthreads();   // D: WB(W2) ready

        // ---- issue W1(c+1) loads AFTER barrier D: in flight during GEMM2 ----
        if (c + 1 < NCHUNK) {
#pragma unroll
            for (int i = 0; i < 6; ++i)
                r1[i] = g1base[(c + 1) * (KC * DIN_ / 4) + tid + NT * i];
        }

        // ---- GEMM2: y[256][128] += relu_h[256][64] @ W2c^T ----
        // wave mapping 4x2: each wave owns 64 rows x 64 cols
        const int wr = w >> 1, wc2 = w & 1;
#pragma unroll
        for (int kk = 0; kk < KC / 32; ++kk) {      // 2 k-steps
            bf16x8 af[4], bfr[4];
#pragma unroll
            for (int mf = 0; mf < 4; ++mf) {
                int r = wr * 64 + mf * 16 + lr;
                af[mf] = *(const bf16x8*)&HB[swz(r, KC, kk * 64 + lg * 16)];
            }
#pragma unroll
            for (int nf = 0; nf < 4; ++nf) {
                int r = wc2 * 64 + nf * 16 + lr;
                bfr[nf] = *(const bf16x8*)&WB[swz(r, KC, kk * 64 + lg * 16)];
            }
#pragma unroll
            for (int mf = 0; mf < 4; ++mf)
#pragma unroll
                for (int nf = 0; nf < 4; ++nf)
                    acc2[mf][nf] = __builtin_amdgcn_mfma_f32_16x16x32_bf16(af[mf], bfr[nf], acc2[mf][nf], 0, 0, 0);
        }
    }

    // ---- final epilogue: y = acc2 + b2 (fp32 out) ----
    const int wr = w >> 1, wc2 = w & 1;
    float b2v[4];
#pragma unroll
    for (int nf = 0; nf < 4; ++nf)
        b2v[nf] = b2[e * DO_ + wc2 * 64 + nf * 16 + lr];
#pragma unroll
    for (int mf = 0; mf < 4; ++mf)
#pragma unroll
        for (int nf = 0; nf < 4; ++nf)
#pragma unroll
            for (int j = 0; j < 4; ++j) {
                int m = wr * 64 + mf * 16 + lg * 4 + j;
                int o = wc2 * 64 + nf * 16 + lr;
                out[(size_t)(e * B_ + row0 + m) * DO_ + o] = acc2[mf][nf][j] + b2v[nf];
            }
}

extern "C" void kernel_launch(void* const* d_in, const int* in_sizes, int n_in,
                              void* d_out, int out_size, void* d_ws, size_t ws_size,
                              hipStream_t stream) {
    const float* x    = (const float*)d_in[0];
    const float* cond = (const float*)d_in[1];
    const float* W1   = (const float*)d_in[2];
    const float* b1   = (const float*)d_in[3];
    const float* W2   = (const float*)d_in[4];
    const float* b2   = (const float*)d_in[5];
    float* out = (float*)d_out;

    dim3 grid(E_ * (B_ / BM));   // 256 blocks = 1 per CU
    dim3 block(NT);              // 512 threads = 8 waves
    moe_fused_kernel<<<grid, block, 0, stream>>>(x, cond, W1, b1, W2, b2, out);
}